// Round 2
// baseline (584.707 us; speedup 1.0000x reference)
//
#include <hip/hip_runtime.h>

// ---------------------------------------------------------------------------
// Self-attention (B=2,S=2048,H=2048,NH=16,HD=128), fp32 in/out, fp16 MFMA core
// Pipeline: f32->f16 convs -> QKV GEMM -> flash attention (causal) -> out GEMM
// Workspace layout (bytes):
//   [0,         25165824)  w_qkv fp16  [6144][2048]
//   [25165824,  33554432)  w_o   fp16  [2048][2048]
//   [33554432,  50331648)  X fp16 [4096][2048]   (reused later as ctx fp16)
//   [50331648,  67108864)  Q fp16 [B][NH][S][HD] (pre-scaled by 1/sqrt(HD))
//   [67108864,  83886080)  K fp16 [B][NH][S][HD]
//   [83886080, 100663296)  V fp16 [B][NH][S][HD]
// Total ws needed: 100,663,296 bytes.
// ---------------------------------------------------------------------------

typedef _Float16 half_t;
typedef _Float16 f16x8 __attribute__((ext_vector_type(8)));
typedef _Float16 f16x4 __attribute__((ext_vector_type(4)));
typedef float f32x4 __attribute__((ext_vector_type(4)));

#define AS3(p) ((__attribute__((address_space(3))) void*)(p))
#define AS1(p) ((const __attribute__((address_space(1))) void*)(p))

constexpr int B_ = 2, S_ = 2048, H_ = 2048, NH_ = 16, HD_ = 128;
constexpr int M_ = B_ * S_;      // 4096 tokens
constexpr int NQKV_ = 3 * H_;    // 6144

// ---------------------------------------------------------------------------
__global__ void f32_to_f16_kernel(const float* __restrict__ src,
                                  half_t* __restrict__ dst, int n4) {
  int i = blockIdx.x * blockDim.x + threadIdx.x;
  int stride = gridDim.x * blockDim.x;
  for (; i < n4; i += stride) {
    float4 f = reinterpret_cast<const float4*>(src)[i];
    f16x4 h;
    h[0] = (half_t)f.x; h[1] = (half_t)f.y; h[2] = (half_t)f.z; h[3] = (half_t)f.w;
    reinterpret_cast<f16x4*>(dst)[i] = h;
  }
}

// ---------------------------------------------------------------------------
// NT GEMM: C[M][N] = A[M][K] * Bw[N][K]^T + bias, K=2048, 128x128 tile, BK=64.
// 256 threads = 4 waves in 2x2; each wave owns a 64x64 output sub-tile.
// LDS tiles swizzled via byte ^= ((row&7)<<4) (applied on the pre-swizzled
// global source for global_load_lds, and on the ds_read side — rule #21:
// linear dest + inverse-swizzled source + swizzled read).
// EPI==0: scatter to Q/K/V [B][NH][S][HD] fp16 (Q scaled by 1/sqrt(HD)).
// EPI==1: fp32 out [M][N] + bias.
template <int EPI>
__global__ __launch_bounds__(256, 2) void gemm_nt(
    const half_t* __restrict__ A, const half_t* __restrict__ Bw,
    const float* __restrict__ bias,
    half_t* __restrict__ qp, half_t* __restrict__ kp, half_t* __restrict__ vp,
    float* __restrict__ outp) {
  constexpr int K_ = 2048;
  __shared__ __align__(16) half_t As[128 * 64];
  __shared__ __align__(16) half_t Bs[128 * 64];
  const int tid = threadIdx.x;
  const int lane = tid & 63;
  const int w = tid >> 6;
  const int wr = w >> 1, wc = w & 1;
  const int l15 = lane & 15, lg = lane >> 4;
  const int rowBase = blockIdx.y * 128;
  const int colBase = blockIdx.x * 128;

  f32x4 acc[4][4];
#pragma unroll
  for (int m = 0; m < 4; ++m)
#pragma unroll
    for (int n = 0; n < 4; ++n) acc[m][n] = {0.f, 0.f, 0.f, 0.f};

  for (int k0 = 0; k0 < K_; k0 += 64) {
    // ---- stage A,B tiles: 128 rows x 64 halves = 16KB each, 4 passes
#pragma unroll
    for (int pass = 0; pass < 4; ++pass) {
      int p = pass * 4096 + tid * 16;           // byte offset in tile
      int row = p >> 7;                         // 128B per row
      int q = (p & 127) ^ ((row & 7) << 4);     // pre-swizzled source byte
      const half_t* ga = &A[(size_t)(rowBase + row) * K_ + k0 + (q >> 1)];
      __builtin_amdgcn_global_load_lds(AS1(ga), AS3((char*)As + (p & ~1023)), 16, 0, 0);
      const half_t* gb = &Bw[(size_t)(colBase + row) * K_ + k0 + (q >> 1)];
      __builtin_amdgcn_global_load_lds(AS1(gb), AS3((char*)Bs + (p & ~1023)), 16, 0, 0);
    }
    __syncthreads();
    // ---- compute: 2 k-chunks of 32, 4x4 fragments of 16x16
#pragma unroll
    for (int kk = 0; kk < 2; ++kk) {
      f16x8 af[4], bf[4];
#pragma unroll
      for (int m = 0; m < 4; ++m) {
        int row = wr * 64 + m * 16 + l15;
        int byte = row * 128 + ((kk * 64 + lg * 16) ^ ((row & 7) << 4));
        af[m] = *reinterpret_cast<const f16x8*>((const char*)As + byte);
      }
#pragma unroll
      for (int n = 0; n < 4; ++n) {
        int row = wc * 64 + n * 16 + l15;
        int byte = row * 128 + ((kk * 64 + lg * 16) ^ ((row & 7) << 4));
        bf[n] = *reinterpret_cast<const f16x8*>((const char*)Bs + byte);
      }
#pragma unroll
      for (int m = 0; m < 4; ++m)
#pragma unroll
        for (int n = 0; n < 4; ++n)
          acc[m][n] = __builtin_amdgcn_mfma_f32_16x16x32_f16(af[m], bf[n], acc[m][n], 0, 0, 0);
    }
    __syncthreads();
  }

  // ---- epilogue (C/D layout: col = lane&15, row = (lane>>4)*4 + reg)
#pragma unroll
  for (int m = 0; m < 4; ++m) {
    int trow = rowBase + wr * 64 + m * 16 + lg * 4;
#pragma unroll
    for (int n = 0; n < 4; ++n) {
      int col = colBase + wc * 64 + n * 16 + l15;
      float bv = bias[col];
      if constexpr (EPI == 0) {
        int which = col >> 11;       // 0=q 1=k 2=v
        int rem = col & 2047;
        int head = rem >> 7;
        int d = rem & 127;
        half_t* dst = (which == 0) ? qp : ((which == 1) ? kp : vp);
        float scl = (which == 0) ? 0.08838834764831845f : 1.0f;
#pragma unroll
        for (int r = 0; r < 4; ++r) {
          int t = trow + r;
          int b = t >> 11, s = t & 2047;
          float v = (acc[m][n][r] + bv) * scl;
          dst[((size_t)((b * NH_ + head) * S_ + s)) * HD_ + d] = (half_t)v;
        }
      } else {
#pragma unroll
        for (int r = 0; r < 4; ++r) {
          int t = trow + r;
          outp[(size_t)t * H_ + col] = acc[m][n][r] + bv;
        }
      }
    }
  }
}

// ---------------------------------------------------------------------------
// Flash attention, causal (mask == tril). Grid: (S/64, B*NH). 4 waves/block,
// each wave owns 16 q-rows. KV tiles of 64. Scores masked to exactly -10000
// (matches reference: s*m - 10000*(1-m); exp underflow identical to ref).
__global__ __launch_bounds__(256, 2) void attn_kernel(
    const half_t* __restrict__ qp, const half_t* __restrict__ kp,
    const half_t* __restrict__ vp, half_t* __restrict__ ctx) {
  __shared__ __align__(16) half_t Ks[64 * 128];   // [kv][128] swizzled rows (256B)
  __shared__ __align__(16) half_t Vt[128 * 72];   // [d][kv] padded 64->72
  __shared__ __align__(16) half_t Ps[4][16 * 72]; // per-wave P [16][kv] padded

  const int tid = threadIdx.x;
  const int lane = tid & 63;
  const int w = tid >> 6;
  const int l15 = lane & 15, lg = lane >> 4;
  const int bh = blockIdx.y;            // b*NH + h
  const int q0 = blockIdx.x * 64;
  const int qw = q0 + w * 16;           // wave's first q row

  // Q fragments in registers (A-layout: row = lane&15, k = (lane>>4)*8+j)
  f16x8 qf[4];
  {
    const half_t* qbase = qp + ((size_t)bh * S_ + qw + l15) * HD_;
#pragma unroll
    for (int kk = 0; kk < 4; ++kk)
      qf[kk] = *reinterpret_cast<const f16x8*>(qbase + kk * 32 + lg * 8);
  }

  f32x4 oacc[8];
#pragma unroll
  for (int d = 0; d < 8; ++d) oacc[d] = {0.f, 0.f, 0.f, 0.f};
  float mrun[4], lrun[4];
#pragma unroll
  for (int r = 0; r < 4; ++r) { mrun[r] = -1e30f; lrun[r] = 0.f; }

  const int nt = blockIdx.x + 1;        // causal: only tiles with k0 <= q0+63
  for (int t = 0; t < nt; ++t) {
    const int k0 = t * 64;
    __syncthreads();  // all waves done reading previous K/Vt
    // ---- stage K [64][128] via swizzled-source global_load_lds (16KB, 4 passes)
#pragma unroll
    for (int pass = 0; pass < 4; ++pass) {
      int p = pass * 4096 + tid * 16;
      int row = p >> 8;                       // 256B per row
      int q = (p & 255) ^ ((row & 7) << 4);
      const half_t* g = &kp[((size_t)bh * S_ + k0 + row) * HD_ + (q >> 1)];
      __builtin_amdgcn_global_load_lds(AS1(g), AS3((char*)Ks + (p & ~1023)), 16, 0, 0);
    }
    // ---- stage V transposed: read [kv][d] coalesced, write Vt[d][kv].
    // Per-lane rotated j-order: without it, the 16 same-kv lanes write
    // addr=(c8+j)*144 -> bank 4j for ALL of them (16-way conflict). With
    // jj=(j+lane)&7 the 16 lanes spread across 8 bank-groups (~2-way, free).
#pragma unroll
    for (int pass = 0; pass < 4; ++pass) {
      int slot = pass * 256 + tid;
      int kv = slot >> 4;
      int m16 = slot & 15;
      int c8 = m16 * 8;
      f16x8 v8 = *reinterpret_cast<const f16x8*>(
          &vp[((size_t)bh * S_ + k0 + kv) * HD_ + c8]);
#pragma unroll
      for (int j = 0; j < 8; ++j) {
        int jj = (j + m16) & 7;
        Vt[(c8 + jj) * 72 + kv] = v8[jj];
      }
    }
    __syncthreads();

    // ---- QK^T: scores [16 q][64 kv], fp32 acc
    f32x4 sc[4];
#pragma unroll
    for (int c = 0; c < 4; ++c) sc[c] = {0.f, 0.f, 0.f, 0.f};
#pragma unroll
    for (int kk = 0; kk < 4; ++kk) {
#pragma unroll
      for (int c = 0; c < 4; ++c) {
        int row = c * 16 + l15;
        int byte = row * 256 + ((kk * 64 + lg * 16) ^ ((row & 7) << 4));
        f16x8 kf = *reinterpret_cast<const f16x8*>((const char*)Ks + byte);
        sc[c] = __builtin_amdgcn_mfma_f32_16x16x32_f16(qf[kk], kf, sc[c], 0, 0, 0);
      }
    }

    // ---- causal mask (exact -10000, as in reference) + online softmax
    float tmax[4];
#pragma unroll
    for (int r = 0; r < 4; ++r) tmax[r] = -1e30f;
#pragma unroll
    for (int c = 0; c < 4; ++c) {
      int kg = k0 + c * 16 + l15;
#pragma unroll
      for (int r = 0; r < 4; ++r) {
        int qg = qw + lg * 4 + r;
        float s = (kg <= qg) ? sc[c][r] : -10000.0f;
        sc[c][r] = s;
        tmax[r] = fmaxf(tmax[r], s);
      }
    }
#pragma unroll
    for (int r = 0; r < 4; ++r)
#pragma unroll
      for (int x = 1; x < 16; x <<= 1)
        tmax[r] = fmaxf(tmax[r], __shfl_xor(tmax[r], x));

    float alpha[4], rsum[4];
#pragma unroll
    for (int r = 0; r < 4; ++r) {
      float mnew = fmaxf(mrun[r], tmax[r]);
      alpha[r] = __expf(mrun[r] - mnew);
      mrun[r] = mnew;
      rsum[r] = 0.f;
    }
#pragma unroll
    for (int c = 0; c < 4; ++c)
#pragma unroll
      for (int r = 0; r < 4; ++r) {
        float pv = __expf(sc[c][r] - mrun[r]);
        sc[c][r] = pv;
        rsum[r] += pv;
      }
#pragma unroll
    for (int r = 0; r < 4; ++r) {
#pragma unroll
      for (int x = 1; x < 16; x <<= 1) rsum[r] += __shfl_xor(rsum[r], x);
      lrun[r] = lrun[r] * alpha[r] + rsum[r];
    }
#pragma unroll
    for (int d = 0; d < 8; ++d)
#pragma unroll
      for (int r = 0; r < 4; ++r) oacc[d][r] *= alpha[r];

    // ---- P (C-layout) -> LDS -> A-layout fragments
    half_t* pw = &Ps[w][0];
#pragma unroll
    for (int c = 0; c < 4; ++c)
#pragma unroll
      for (int r = 0; r < 4; ++r)
        pw[(lg * 4 + r) * 72 + c * 16 + l15] = (half_t)sc[c][r];

    f16x8 pf[2];
#pragma unroll
    for (int kk = 0; kk < 2; ++kk)
      pf[kk] = *reinterpret_cast<const f16x8*>(&pw[l15 * 72 + kk * 32 + lg * 8]);

    // ---- PV: O[16 q][128 d] += P[16][64] * V[64][128]
#pragma unroll
    for (int dc = 0; dc < 8; ++dc) {
#pragma unroll
      for (int kk = 0; kk < 2; ++kk) {
        f16x8 vf = *reinterpret_cast<const f16x8*>(
            &Vt[(dc * 16 + l15) * 72 + kk * 32 + lg * 8]);
        oacc[dc] = __builtin_amdgcn_mfma_f32_16x16x32_f16(pf[kk], vf, oacc[dc], 0, 0, 0);
      }
    }
  }

  // ---- write ctx [b][s][H] fp16
  const int b = bh >> 4, h = bh & 15;
#pragma unroll
  for (int dc = 0; dc < 8; ++dc)
#pragma unroll
    for (int r = 0; r < 4; ++r) {
      int s = qw + lg * 4 + r;
      float v = oacc[dc][r] / lrun[r];
      ctx[((size_t)(b * S_ + s)) * H_ + h * HD_ + dc * 16 + l15] = (half_t)v;
    }
}

// ---------------------------------------------------------------------------
extern "C" void kernel_launch(void* const* d_in, const int* in_sizes, int n_in,
                              void* d_out, int out_size, void* d_ws, size_t ws_size,
                              hipStream_t stream) {
  (void)in_sizes; (void)n_in; (void)out_size; (void)ws_size;
  const float* hidden = (const float*)d_in[0];
  // d_in[1] is the multiplicative causal mask; causality is implemented directly.
  const float* w_qkv = (const float*)d_in[2];
  const float* b_qkv = (const float*)d_in[3];
  const float* w_o   = (const float*)d_in[4];
  const float* b_o   = (const float*)d_in[5];
  float* out = (float*)d_out;

  char* ws = (char*)d_ws;
  half_t* wqkvb = (half_t*)(ws + 0);          // 25,165,824 B
  half_t* wob   = (half_t*)(ws + 25165824);   //  8,388,608 B
  half_t* xb    = (half_t*)(ws + 33554432);   // 16,777,216 B (reused as ctx)
  half_t* qws   = (half_t*)(ws + 50331648);   // 16,777,216 B
  half_t* kws   = (half_t*)(ws + 67108864);   // 16,777,216 B
  half_t* vws   = (half_t*)(ws + 83886080);   // 16,777,216 B -> end 100,663,296
  half_t* ctx   = xb;  // safe: xb consumed by gemm_nt<0> before attn writes ctx

  f32_to_f16_kernel<<<2048, 256, 0, stream>>>(hidden, xb, M_ * H_ / 4);
  f32_to_f16_kernel<<<2048, 256, 0, stream>>>(w_qkv, wqkvb, NQKV_ * H_ / 4);
  f32_to_f16_kernel<<<2048, 256, 0, stream>>>(w_o, wob, H_ * H_ / 4);

  gemm_nt<0><<<dim3(NQKV_ / 128, M_ / 128), 256, 0, stream>>>(
      xb, wqkvb, b_qkv, qws, kws, vws, nullptr);

  attn_kernel<<<dim3(S_ / 64, B_ * NH_), 256, 0, stream>>>(qws, kws, vws, ctx);

  gemm_nt<1><<<dim3(H_ / 128, M_ / 128), 256, 0, stream>>>(
      ctx, wob, b_o, nullptr, nullptr, nullptr, out);
}

// Round 8
// 457.176 us; speedup vs baseline: 1.2790x; 1.2790x over previous
//
#include <hip/hip_runtime.h>

// ---------------------------------------------------------------------------
// Self-attention (B=2,S=2048,H=2048,NH=16,HD=128), fp32 in/out, fp16 MFMA core
// Pipeline: f32->f16 convs -> QKV GEMM -> flash attention (causal) -> out GEMM
// R2-R7: swapped-operand attention (S^T = K*Q^T, O^T = V^T*P^T), V stored
// transposed in global by the QKV epilogue, P relayout fully in-register.
// R4: + XCD-aware chunked block swizzle on both GEMMs (bijective, nwg%8==0).
// Workspace layout (bytes):
//   [0,         25165824)  w_qkv fp16  [6144][2048]
//   [25165824,  33554432)  w_o   fp16  [2048][2048]
//   [33554432,  50331648)  X fp16 [4096][2048]   (reused later as ctx fp16)
//   [50331648,  67108864)  Q fp16 [B][NH][S][HD] (pre-scaled by 1/sqrt(HD))
//   [67108864,  83886080)  K fp16 [B][NH][S][HD]
//   [83886080, 100663296)  V^T fp16 [B][NH][HD][S]   (transposed!)
// Total ws needed: 100,663,296 bytes.
// ---------------------------------------------------------------------------

typedef _Float16 half_t;
typedef _Float16 f16x8 __attribute__((ext_vector_type(8)));
typedef _Float16 f16x4 __attribute__((ext_vector_type(4)));
typedef float f32x4 __attribute__((ext_vector_type(4)));

#define AS3(p) ((__attribute__((address_space(3))) void*)(p))
#define AS1(p) ((const __attribute__((address_space(1))) void*)(p))

constexpr int B_ = 2, S_ = 2048, H_ = 2048, NH_ = 16, HD_ = 128;
constexpr int M_ = B_ * S_;      // 4096 tokens
constexpr int NQKV_ = 3 * H_;    // 6144

union U2H4 { uint2 u; f16x4 h; };
union U4H8 { uint4 u; f16x8 h; };

// ---------------------------------------------------------------------------
__global__ void f32_to_f16_kernel(const float* __restrict__ src,
                                  half_t* __restrict__ dst, int n4) {
  int i = blockIdx.x * blockDim.x + threadIdx.x;
  int stride = gridDim.x * blockDim.x;
  for (; i < n4; i += stride) {
    float4 f = reinterpret_cast<const float4*>(src)[i];
    f16x4 h;
    h[0] = (half_t)f.x; h[1] = (half_t)f.y; h[2] = (half_t)f.z; h[3] = (half_t)f.w;
    reinterpret_cast<f16x4*>(dst)[i] = h;
  }
}

// ---------------------------------------------------------------------------
// NT GEMM: C[M][N] = A[M][K] * Bw[N][K]^T + bias, K=2048, 128x128 tile, BK=64.
// 1D grid of GX*GY blocks, XCD-chunked remap (each XCD gets a contiguous
// orig-id range -> its A-panels stay L2-resident). Requires (GX*GY)%8==0.
// EPI==0: scatter Q,K -> [B][NH][S][HD], V -> [B][NH][HD][S] (transposed).
// EPI==1: fp32 out [M][N] + bias.
template <int EPI, int GX, int GY>
__global__ __launch_bounds__(256, 2) void gemm_nt(
    const half_t* __restrict__ A, const half_t* __restrict__ Bw,
    const float* __restrict__ bias,
    half_t* __restrict__ qp, half_t* __restrict__ kp, half_t* __restrict__ vp,
    float* __restrict__ outp) {
  constexpr int K_ = 2048;
  constexpr int NWG = GX * GY;
  static_assert(NWG % 8 == 0, "bijective chunked swizzle needs nwg%8==0");
  __shared__ __align__(16) half_t As[128 * 64];
  __shared__ __align__(16) half_t Bs[128 * 64];
  const int tid = threadIdx.x;
  const int lane = tid & 63;
  const int w = tid >> 6;
  const int wr = w >> 1, wc = w & 1;
  const int l15 = lane & 15, lg = lane >> 4;
  // XCD-aware chunked swizzle: hw block h runs on XCD h%8; give XCD x the
  // contiguous original range [x*NWG/8, (x+1)*NWG/8).
  const int h = blockIdx.x;
  const int orig = (h & 7) * (NWG / 8) + (h >> 3);
  const int rowBase = (orig / GX) * 128;
  const int colBase = (orig % GX) * 128;

  f32x4 acc[4][4];
#pragma unroll
  for (int m = 0; m < 4; ++m)
#pragma unroll
    for (int n = 0; n < 4; ++n) acc[m][n] = {0.f, 0.f, 0.f, 0.f};

  for (int k0 = 0; k0 < K_; k0 += 64) {
#pragma unroll
    for (int pass = 0; pass < 4; ++pass) {
      int p = pass * 4096 + tid * 16;           // byte offset in tile
      int row = p >> 7;                         // 128B per row
      int q = (p & 127) ^ ((row & 7) << 4);     // pre-swizzled source byte
      const half_t* ga = &A[(size_t)(rowBase + row) * K_ + k0 + (q >> 1)];
      __builtin_amdgcn_global_load_lds(AS1(ga), AS3((char*)As + (p & ~1023)), 16, 0, 0);
      const half_t* gb = &Bw[(size_t)(colBase + row) * K_ + k0 + (q >> 1)];
      __builtin_amdgcn_global_load_lds(AS1(gb), AS3((char*)Bs + (p & ~1023)), 16, 0, 0);
    }
    __syncthreads();
#pragma unroll
    for (int kk = 0; kk < 2; ++kk) {
      f16x8 af[4], bf[4];
#pragma unroll
      for (int m = 0; m < 4; ++m) {
        int row = wr * 64 + m * 16 + l15;
        int byte = row * 128 + ((kk * 64 + lg * 16) ^ ((row & 7) << 4));
        af[m] = *reinterpret_cast<const f16x8*>((const char*)As + byte);
      }
#pragma unroll
      for (int n = 0; n < 4; ++n) {
        int row = wc * 64 + n * 16 + l15;
        int byte = row * 128 + ((kk * 64 + lg * 16) ^ ((row & 7) << 4));
        bf[n] = *reinterpret_cast<const f16x8*>((const char*)Bs + byte);
      }
#pragma unroll
      for (int m = 0; m < 4; ++m)
#pragma unroll
        for (int n = 0; n < 4; ++n)
          acc[m][n] = __builtin_amdgcn_mfma_f32_16x16x32_f16(af[m], bf[n], acc[m][n], 0, 0, 0);
    }
    __syncthreads();
  }

  // ---- epilogue (C/D layout: col = lane&15, row = (lane>>4)*4 + reg)
#pragma unroll
  for (int m = 0; m < 4; ++m) {
    int trow = rowBase + wr * 64 + m * 16 + lg * 4;
#pragma unroll
    for (int n = 0; n < 4; ++n) {
      int col = colBase + wc * 64 + n * 16 + l15;
      float bv = bias[col];
      if constexpr (EPI == 0) {
        int which = col >> 11;       // 0=q 1=k 2=v
        int rem = col & 2047;
        int head = rem >> 7;
        int d = rem & 127;
        float scl = (which == 0) ? 0.08838834764831845f : 1.0f;
#pragma unroll
        for (int r = 0; r < 4; ++r) {
          int t = trow + r;
          int b = t >> 11, s = t & 2047;
          float v = (acc[m][n][r] + bv) * scl;
          if (which == 2) {
            vp[((size_t)((b * NH_ + head) * HD_ + d)) * S_ + s] = (half_t)v;
          } else {
            half_t* dst = (which == 0) ? qp : kp;
            dst[((size_t)((b * NH_ + head) * S_ + s)) * HD_ + d] = (half_t)v;
          }
        }
      } else {
#pragma unroll
        for (int r = 0; r < 4; ++r) {
          int t = trow + r;
          outp[(size_t)t * H_ + col] = acc[m][n][r] + bv;
        }
      }
    }
  }
}

// ---------------------------------------------------------------------------
// Flash attention, causal. Grid: (S/64 qtiles reversed, B*NH). 4 waves/block,
// each wave owns 16 q-rows. KV tiles of 64.
// Swapped operands: S^T = mfma(K,Q) -> lane owns one q (col=l15), k spread
// over (c,lg,r). Softmax per-lane scalar stats + 2 shuffles. P relayout
// C-frag -> B-frag in-register (shfl within 4-lane column groups).
// PV: O^T = mfma(VtFrag, P) with V^T staged from global [b][h][d][s].
__global__ __launch_bounds__(256, 4) void attn_kernel(
    const half_t* __restrict__ qp, const half_t* __restrict__ kp,
    const half_t* __restrict__ vtp, half_t* __restrict__ ctx) {
  __shared__ __align__(16) half_t Ks[64 * 128];   // [kv][hd]  256B rows, swizzled
  __shared__ __align__(16) half_t Vt[128 * 64];   // [d][kv]   128B rows, swizzled

  const int tid = threadIdx.x;
  const int lane = tid & 63;
  const int w = tid >> 6;
  const int l15 = lane & 15, lg = lane >> 4;
  const int bh = blockIdx.y;                  // b*NH + h
  const int qtile = (gridDim.x - 1) - blockIdx.x;   // heavy blocks first
  const int q0 = qtile * 64;
  const int qw = q0 + w * 16;                 // wave's first q row
  const int myq = qw + l15;                   // this lane's q row

  // Q fragment (B-layout: col=lane&15 -> q, k = (lane>>4)*8+j)
  f16x8 qf[4];
  {
    const half_t* qbase = qp + ((size_t)bh * S_ + myq) * HD_;
#pragma unroll
    for (int kk = 0; kk < 4; ++kk)
      qf[kk] = *reinterpret_cast<const f16x8*>(qbase + kk * 32 + lg * 8);
  }

  f32x4 oacc[8];                              // O^T: col=l15=q, row=d (lg*4+r)+dc*16
#pragma unroll
  for (int d = 0; d < 8; ++d) oacc[d] = {0.f, 0.f, 0.f, 0.f};
  float mrun = -1e30f, lrun = 0.f;            // per-lane scalars (one q per lane)

  const int nt = qtile + 1;
  for (int t = 0; t < nt; ++t) {
    const int k0 = t * 64;
    __syncthreads();  // previous tile's LDS reads done
    // ---- stage K [64 kv][128 hd] (16KB) via swizzled-source global_load_lds
#pragma unroll
    for (int pass = 0; pass < 4; ++pass) {
      int p = pass * 4096 + tid * 16;
      int row = p >> 8;                       // 256B per row
      int q = (p & 255) ^ ((row & 7) << 4);
      const half_t* g = &kp[((size_t)bh * S_ + k0 + row) * HD_ + (q >> 1)];
      __builtin_amdgcn_global_load_lds(AS1(g), AS3((char*)Ks + (p & ~1023)), 16, 0, 0);
    }
    // ---- stage V^T [128 d][64 kv] (16KB) straight from global (no transpose!)
#pragma unroll
    for (int pass = 0; pass < 4; ++pass) {
      int p = pass * 4096 + tid * 16;
      int row = p >> 7;                       // 128B per row
      int q = (p & 127) ^ ((row & 7) << 4);
      const half_t* g = &vtp[((size_t)bh * HD_ + row) * S_ + k0 + (q >> 1)];
      __builtin_amdgcn_global_load_lds(AS1(g), AS3((char*)Vt + (p & ~1023)), 16, 0, 0);
    }
    __syncthreads();

    // ---- S^T = K * Q^T : C col=l15 -> q, row = c*16+lg*4+r -> k
    f32x4 sc[4];
#pragma unroll
    for (int c = 0; c < 4; ++c) sc[c] = {0.f, 0.f, 0.f, 0.f};
#pragma unroll
    for (int kk = 0; kk < 4; ++kk) {
#pragma unroll
      for (int c = 0; c < 4; ++c) {
        int row = c * 16 + l15;
        int byte = row * 256 + ((kk * 64 + lg * 16) ^ ((row & 7) << 4));
        f16x8 kf = *reinterpret_cast<const f16x8*>((const char*)Ks + byte);
        sc[c] = __builtin_amdgcn_mfma_f32_16x16x32_f16(kf, qf[kk], sc[c], 0, 0, 0);
      }
    }

    // ---- causal mask (exact -10000, matches reference) + per-lane softmax
    float tm = -1e30f;
#pragma unroll
    for (int c = 0; c < 4; ++c) {
#pragma unroll
      for (int r = 0; r < 4; ++r) {
        int kg = k0 + c * 16 + lg * 4 + r;
        float s = (kg <= myq) ? sc[c][r] : -10000.0f;
        sc[c][r] = s;
        tm = fmaxf(tm, s);
      }
    }
    tm = fmaxf(tm, __shfl_xor(tm, 16));
    tm = fmaxf(tm, __shfl_xor(tm, 32));

    float mnew = fmaxf(mrun, tm);
    float alpha = __expf(mrun - mnew);
    mrun = mnew;
    float rs = 0.f;
#pragma unroll
    for (int c = 0; c < 4; ++c)
#pragma unroll
      for (int r = 0; r < 4; ++r) {
        float pv = __expf(sc[c][r] - mrun);
        sc[c][r] = pv;
        rs += pv;
      }
    rs += __shfl_xor(rs, 16);
    rs += __shfl_xor(rs, 32);
    lrun = lrun * alpha + rs;
#pragma unroll
    for (int d = 0; d < 8; ++d) oacc[d] *= alpha;

    // ---- P relayout: C-frag (col=q, row=k) -> B-frag (col=q, k=lg*8+j),
    // all in-register. Source lane for target (lg, half h): same l15,
    // lg' = (2*lg+h)&3; source c-frag = 2*kk + (lg>>1).
    uint2 pp[4];
#pragma unroll
    for (int c = 0; c < 4; ++c) {
      U2H4 u;
      u.h[0] = (half_t)sc[c][0]; u.h[1] = (half_t)sc[c][1];
      u.h[2] = (half_t)sc[c][2]; u.h[3] = (half_t)sc[c][3];
      pp[c] = u.u;
    }
    const int sA = (((2 * lg) & 3) << 4) + l15;
    const int sB = (((2 * lg + 1) & 3) << 4) + l15;
    const bool hi = (lg >= 2);
    f16x8 pf[2];
#pragma unroll
    for (int kk = 0; kk < 2; ++kk) {
      uint2 e = pp[2 * kk], o = pp[2 * kk + 1];
      uint2 ae, ao, be, bo;
      ae.x = __shfl((int)e.x, sA); ae.y = __shfl((int)e.y, sA);
      ao.x = __shfl((int)o.x, sA); ao.y = __shfl((int)o.y, sA);
      be.x = __shfl((int)e.x, sB); be.y = __shfl((int)e.y, sB);
      bo.x = __shfl((int)o.x, sB); bo.y = __shfl((int)o.y, sB);
      uint2 first = hi ? ao : ae;
      uint2 second = hi ? bo : be;
      U4H8 u; u.u = make_uint4(first.x, first.y, second.x, second.y);
      pf[kk] = u.h;
    }

    // ---- O^T += V^T * P^T : A = Vt-frag (row=l15 -> d), B = pf
#pragma unroll
    for (int dc = 0; dc < 8; ++dc) {
      int row = dc * 16 + l15;
#pragma unroll
      for (int kk = 0; kk < 2; ++kk) {
        int byte = row * 128 + ((kk * 64 + lg * 16) ^ ((row & 7) << 4));
        f16x8 vf = *reinterpret_cast<const f16x8*>((const char*)Vt + byte);
        oacc[dc] = __builtin_amdgcn_mfma_f32_16x16x32_f16(vf, pf[kk], oacc[dc], 0, 0, 0);
      }
    }
  }

  // ---- write ctx [b][s][H] fp16; lane holds O[q=myq][d=dc*16+lg*4+r]
  const int b = bh >> 4, h = bh & 15;
  const float rl = 1.0f / lrun;
  half_t* cbase = ctx + ((size_t)(b * S_ + myq)) * H_ + h * HD_;
#pragma unroll
  for (int dc = 0; dc < 8; ++dc) {
    U2H4 u;
    u.h[0] = (half_t)(oacc[dc][0] * rl);
    u.h[1] = (half_t)(oacc[dc][1] * rl);
    u.h[2] = (half_t)(oacc[dc][2] * rl);
    u.h[3] = (half_t)(oacc[dc][3] * rl);
    *reinterpret_cast<uint2*>(cbase + dc * 16 + lg * 4) = u.u;
  }
}

// ---------------------------------------------------------------------------
extern "C" void kernel_launch(void* const* d_in, const int* in_sizes, int n_in,
                              void* d_out, int out_size, void* d_ws, size_t ws_size,
                              hipStream_t stream) {
  (void)in_sizes; (void)n_in; (void)out_size; (void)ws_size;
  const float* hidden = (const float*)d_in[0];
  // d_in[1] is the multiplicative causal mask; causality is implemented directly.
  const float* w_qkv = (const float*)d_in[2];
  const float* b_qkv = (const float*)d_in[3];
  const float* w_o   = (const float*)d_in[4];
  const float* b_o   = (const float*)d_in[5];
  float* out = (float*)d_out;

  char* ws = (char*)d_ws;
  half_t* wqkvb = (half_t*)(ws + 0);          // 25,165,824 B
  half_t* wob   = (half_t*)(ws + 25165824);   //  8,388,608 B
  half_t* xb    = (half_t*)(ws + 33554432);   // 16,777,216 B (reused as ctx)
  half_t* qws   = (half_t*)(ws + 50331648);   // 16,777,216 B
  half_t* kws   = (half_t*)(ws + 67108864);   // 16,777,216 B
  half_t* vtws  = (half_t*)(ws + 83886080);   // 16,777,216 B (V^T [b][h][d][s])
  half_t* ctx   = xb;  // safe: xb consumed by gemm_nt<0> before attn writes ctx

  f32_to_f16_kernel<<<2048, 256, 0, stream>>>(hidden, xb, M_ * H_ / 4);
  f32_to_f16_kernel<<<2048, 256, 0, stream>>>(w_qkv, wqkvb, NQKV_ * H_ / 4);
  f32_to_f16_kernel<<<2048, 256, 0, stream>>>(w_o, wob, H_ * H_ / 4);

  gemm_nt<0, NQKV_ / 128, M_ / 128><<<(NQKV_ / 128) * (M_ / 128), 256, 0, stream>>>(
      xb, wqkvb, b_qkv, qws, kws, vtws, nullptr);

  attn_kernel<<<dim3(S_ / 64, B_ * NH_), 256, 0, stream>>>(qws, kws, vtws, ctx);

  gemm_nt<1, H_ / 128, M_ / 128><<<(H_ / 128) * (M_ / 128), 256, 0, stream>>>(
      ctx, wob, b_o, nullptr, nullptr, nullptr, out);
}